// Round 4
// baseline (505.845 us; speedup 1.0000x reference)
//
#include <hip/hip_runtime.h>
#include <hip/hip_bf16.h>

#define NSRC 65536
#define NDST 8192
#define H 128
#define NP 132   // padded LDS row stride (floats)

// mixing constants: z2sim = 0.34*sim + 0.495*cor@Wcs + 0.165*sim@(Wsc@Wcs) (and sym.)
#define C_SELF 0.34f
#define C_CROSS 0.495f
#define C_DBL  0.165f

static __device__ __forceinline__ float b2f(unsigned short u) {
  union { unsigned int i; float f; } v; v.i = ((unsigned int)u) << 16; return v.f;
}
static __device__ __forceinline__ unsigned short f2b(float f) {
  union { float f; unsigned int i; } v; v.f = f;
  unsigned int x = v.i;
  return (unsigned short)((x + 0x7fffu + ((x >> 16) & 1u)) >> 16);  // RNE
}
static __device__ __forceinline__ void load4bf(const unsigned short* p, float* d) {
  ushort4 u = *(const ushort4*)p;
  d[0] = b2f(u.x); d[1] = b2f(u.y); d[2] = b2f(u.z); d[3] = b2f(u.w);
}
static __device__ __forceinline__ void store4bf(unsigned short* p, const float* d) {
  ushort4 u; u.x = f2b(d[0]); u.y = f2b(d[1]); u.z = f2b(d[2]); u.w = f2b(d[3]);
  *(ushort4*)p = u;
}
// dual-dtype loaders: f32flag=1 -> buffer holds float32, else bf16. idx = element index.
static __device__ __forceinline__ void load4any(const void* base, size_t idx, int f32flag, float* d) {
  if (f32flag) {
    float4 v = *(const float4*)((const float*)base + idx);
    d[0] = v.x; d[1] = v.y; d[2] = v.z; d[3] = v.w;
  } else {
    load4bf((const unsigned short*)base + idx, d);
  }
}
static __device__ __forceinline__ float load1any(const void* base, size_t idx, int f32flag) {
  return f32flag ? ((const float*)base)[idx] : b2f(((const unsigned short*)base)[idx]);
}

// flags[0]=1 iff float tensors are f32 (else bf16). flags[1]=1 iff x is int64 (else int32).
__global__ void detect(const unsigned short* __restrict__ W, const int* __restrict__ x,
                       int* __restrict__ flags) {
  if (threadIdx.x != 0 || blockIdx.x != 0) return;
  int bad = 0;
  for (int i = 0; i < 128; ++i) {
    unsigned short u = W[i];
    if (u != 0) {
      int e = (u >> 7) & 0xFF;
      if (e < 90 || e > 128) bad++;
    }
  }
  flags[0] = (bad > 8) ? 1 : 0;
  int allz = 1;
  for (int r = 0; r < 16; ++r)
    if (x[2 * r + 1] != 0) allz = 0;
  flags[1] = allz;
}

// feat[r,:] = [emb0[x0[r]] | emb1[x1[r]]] @ W + b   (65536 x 128, K=128), bf16 out
__global__ __launch_bounds__(256) void featgemm(
    const int* __restrict__ x,
    const void* __restrict__ emb0,
    const void* __restrict__ emb1,
    const void* __restrict__ W,
    const void* __restrict__ bvec,
    const int* __restrict__ flags,
    unsigned short* __restrict__ feat)
{
  const int wf  = flags[0];
  const int x64 = flags[1];
  const int t = threadIdx.x;
  const int rt = t >> 5, ct = t & 31;
  const int r0 = blockIdx.x * 32 + rt * 4;
  const int c0 = ct * 4;

  float acc[4][4];
  float bv[4]; load4any(bvec, c0, wf, bv);
#pragma unroll
  for (int i = 0; i < 4; ++i)
#pragma unroll
    for (int j = 0; j < 4; ++j) acc[i][j] = bv[j];

  int x0[4], x1[4];
#pragma unroll
  for (int i = 0; i < 4; ++i) {
    if (x64) { x0[i] = x[(r0 + i) * 4]; x1[i] = x[(r0 + i) * 4 + 2]; }
    else     { x0[i] = x[(r0 + i) * 2]; x1[i] = x[(r0 + i) * 2 + 1]; }
  }

  float a[4][4], w[4];
  for (int k = 0; k < 32; k += 4) {
#pragma unroll
    for (int i = 0; i < 4; ++i) load4any(emb0, (size_t)x0[i] * 32 + k, wf, a[i]);
#pragma unroll
    for (int kk = 0; kk < 4; ++kk) {
      load4any(W, (size_t)(k + kk) * H + c0, wf, w);
#pragma unroll
      for (int i = 0; i < 4; ++i) {
        const float av = a[i][kk];
#pragma unroll
        for (int j = 0; j < 4; ++j) acc[i][j] += av * w[j];
      }
    }
  }
  for (int k = 32; k < 128; k += 4) {
#pragma unroll
    for (int i = 0; i < 4; ++i) load4any(emb1, (size_t)x1[i] * 96 + (k - 32), wf, a[i]);
#pragma unroll
    for (int kk = 0; kk < 4; ++kk) {
      load4any(W, (size_t)(k + kk) * H + c0, wf, w);
#pragma unroll
      for (int i = 0; i < 4; ++i) {
        const float av = a[i][kk];
#pragma unroll
        for (int j = 0; j < 4; ++j) acc[i][j] += av * w[j];
      }
    }
  }
#pragma unroll
  for (int i = 0; i < 4; ++i)
    store4bf(feat + (size_t)(r0 + i) * H + c0, acc[i]);
}

// Per destination node n: collapsed co-attention pool + h_self add. bf16 feat in/out.
__global__ __launch_bounds__(256) void coatt(
    const unsigned short* __restrict__ feat,
    const int* __restrict__ idxD,
    const int* __restrict__ idxQ,
    unsigned short* __restrict__ rst)
{
  __shared__ float Ds[32 * NP];
  __shared__ float Qs[32 * NP];
  __shared__ float Ls[32 * 33];
  __shared__ float EC[32 * 33];
  __shared__ float ES[32 * 33];
  __shared__ float rowmax[32], rowrcp[32], colmax[32], colrcp[32], sv[32], tv[32];
  __shared__ float g[384];

  const int n = blockIdx.x;
  const int t = threadIdx.x;

  for (int s = t; s < 1024; s += 256) {
    const int r = s >> 5, q4 = (s & 31) * 4;
    const int gD = idxD[n * 32 + r], gQ = idxQ[n * 32 + r];
    float dv[4], qv[4];
    load4bf(feat + (size_t)gD * H + q4, dv);
    load4bf(feat + (size_t)gQ * H + q4, qv);
    Ds[r * NP + q4] = dv[0]; Ds[r * NP + q4 + 1] = dv[1];
    Ds[r * NP + q4 + 2] = dv[2]; Ds[r * NP + q4 + 3] = dv[3];
    Qs[r * NP + q4] = qv[0]; Qs[r * NP + q4 + 1] = qv[1];
    Qs[r * NP + q4 + 2] = qv[2]; Qs[r * NP + q4 + 3] = qv[3];
  }
  __syncthreads();

  // L[m,k] = D[m,:] . Q[k,:]
  {
    const int m0 = (t >> 4) * 2, k0 = (t & 15) * 2;
    float a00 = 0, a01 = 0, a10 = 0, a11 = 0;
    for (int h = 0; h < 128; h += 4) {
      float4 d0 = *(const float4*)(Ds + m0 * NP + h);
      float4 d1 = *(const float4*)(Ds + (m0 + 1) * NP + h);
      float4 q0 = *(const float4*)(Qs + k0 * NP + h);
      float4 q1 = *(const float4*)(Qs + (k0 + 1) * NP + h);
      a00 += d0.x * q0.x + d0.y * q0.y + d0.z * q0.z + d0.w * q0.w;
      a01 += d0.x * q1.x + d0.y * q1.y + d0.z * q1.z + d0.w * q1.w;
      a10 += d1.x * q0.x + d1.y * q0.y + d1.z * q0.z + d1.w * q0.w;
      a11 += d1.x * q1.x + d1.y * q1.y + d1.z * q1.z + d1.w * q1.w;
    }
    Ls[m0 * 33 + k0] = a00; Ls[m0 * 33 + k0 + 1] = a01;
    Ls[(m0 + 1) * 33 + k0] = a10; Ls[(m0 + 1) * 33 + k0 + 1] = a11;
  }
  __syncthreads();

  if (t < 32) {                       // row stats (AC: softmax over k)
    float m = -1e30f;
    for (int k = 0; k < 32; ++k) m = fmaxf(m, Ls[t * 33 + k]);
    float s = 0.f;
    for (int k = 0; k < 32; ++k) s += __expf(Ls[t * 33 + k] - m);
    rowmax[t] = m; rowrcp[t] = 1.0f / s;
  } else if (t >= 64 && t < 96) {     // col stats (AS: softmax over m)
    const int c = t - 64;
    float m = -1e30f;
    for (int k = 0; k < 32; ++k) m = fmaxf(m, Ls[k * 33 + c]);
    float s = 0.f;
    for (int k = 0; k < 32; ++k) s += __expf(Ls[k * 33 + c] - m);
    colmax[c] = m; colrcp[c] = 1.0f / s;
  }
  __syncthreads();

  for (int idx = t; idx < 1024; idx += 256) {
    const int m = idx >> 5, k = idx & 31;
    const float Lv = Ls[m * 33 + k];
    EC[m * 33 + k] = __expf(Lv - rowmax[m]) * rowrcp[m];   // AC[m,k]
    ES[m * 33 + k] = __expf(Lv - colmax[k]) * colrcp[k];   // AS[k,m]
  }
  __syncthreads();
  if (t < 32) {        // s[m] = sum_k AS[k,m]
    float s = 0.f;
    for (int k = 0; k < 32; ++k) s += ES[t * 33 + k];
    sv[t] = s;
  }
  __syncthreads();
  if (t < 32) {        // t[k] = sum_m s[m]*AC[m,k]
    float s = 0.f;
    for (int m = 0; m < 32; ++m) s += sv[m] * EC[m * 33 + t];
    tv[t] = s;
  }
  __syncthreads();

  // g = [u | v | w] = [(1/32)sum_k Q | (1/32) s@D | (1/32) t@Q]
  for (int i = t; i < 384; i += 256) {
    float s = 0.f;
    if (i < 128) {
      for (int k = 0; k < 32; ++k) s += Qs[k * NP + i];
    } else if (i < 256) {
      const int h = i - 128;
      for (int m = 0; m < 32; ++m) s += sv[m] * Ds[m * NP + h];
    } else {
      const int h = i - 256;
      for (int k = 0; k < 32; ++k) s += tv[k] * Qs[k * NP + h];
    }
    g[i] = s * 0.03125f;
  }
  __syncthreads();

  if (t < 128) {
    const float pooled = (g[3 * t] + g[3 * t + 1] + g[3 * t + 2]) * (1.0f / 3.0f);
    const float hs = b2f(feat[(size_t)n * H + t]);
    rst[(size_t)n * H + t] = f2b(hs + pooled);
  }
}

// P1 = Wo_s@Wsc, P2 = Wo_c@Wcs, p1 = b_s@Wsc, p2 = b_c@Wcs
__global__ __launch_bounds__(128) void smallmm1(
    const void* __restrict__ Wos, const void* __restrict__ Woc,
    const void* __restrict__ Wsc, const void* __restrict__ Wcs,
    const void* __restrict__ bs, const void* __restrict__ bc,
    const int* __restrict__ flags,
    float* __restrict__ P1, float* __restrict__ P2,
    float* __restrict__ p1, float* __restrict__ p2)
{
  const int wf = flags[0];
  const int bid = blockIdx.x, c = threadIdx.x;
  if (bid < 128) {
    const int r = bid; float acc = 0.f;
    for (int k = 0; k < 128; ++k) acc += load1any(Wos, r * 128 + k, wf) * load1any(Wsc, k * 128 + c, wf);
    P1[r * 128 + c] = acc;
  } else if (bid < 256) {
    const int r = bid - 128; float acc = 0.f;
    for (int k = 0; k < 128; ++k) acc += load1any(Woc, r * 128 + k, wf) * load1any(Wcs, k * 128 + c, wf);
    P2[r * 128 + c] = acc;
  } else if (bid == 256) {
    float acc = 0.f;
    for (int k = 0; k < 128; ++k) acc += load1any(bs, k, wf) * load1any(Wsc, k * 128 + c, wf);
    p1[c] = acc;
  } else {
    float acc = 0.f;
    for (int k = 0; k < 128; ++k) acc += load1any(bc, k, wf) * load1any(Wcs, k * 128 + c, wf);
    p2[c] = acc;
  }
}

// Mss = C_SELF*Wo_s + C_DBL*P1@Wcs ; Mcc = C_SELF*Wo_c + C_DBL*P2@Wsc ; fused biases
__global__ __launch_bounds__(128) void smallmm2(
    const void* __restrict__ Wos, const void* __restrict__ Woc,
    const void* __restrict__ Wsc, const void* __restrict__ Wcs,
    const void* __restrict__ bs, const void* __restrict__ bc,
    const int* __restrict__ flags,
    const float* __restrict__ P1, const float* __restrict__ P2,
    const float* __restrict__ p1, const float* __restrict__ p2,
    float* __restrict__ Mss, float* __restrict__ Mcc,
    float* __restrict__ bsim, float* __restrict__ bcor)
{
  const int wf = flags[0];
  const int bid = blockIdx.x, c = threadIdx.x;
  if (bid < 128) {
    const int r = bid; float acc = 0.f;
    for (int k = 0; k < 128; ++k) acc += P1[r * 128 + k] * load1any(Wcs, k * 128 + c, wf);
    Mss[r * 128 + c] = C_SELF * load1any(Wos, r * 128 + c, wf) + C_DBL * acc;
  } else if (bid < 256) {
    const int r = bid - 128; float acc = 0.f;
    for (int k = 0; k < 128; ++k) acc += P2[r * 128 + k] * load1any(Wsc, k * 128 + c, wf);
    Mcc[r * 128 + c] = C_SELF * load1any(Woc, r * 128 + c, wf) + C_DBL * acc;
  } else if (bid == 256) {
    float acc = 0.f;
    for (int k = 0; k < 128; ++k) acc += p1[k] * load1any(Wcs, k * 128 + c, wf);
    bsim[c] = C_SELF * load1any(bs, c, wf) + C_CROSS * p2[c] + C_DBL * acc;
  } else {
    float acc = 0.f;
    for (int k = 0; k < 128; ++k) acc += p2[k] * load1any(Wsc, k * 128 + c, wf);
    bcor[c] = C_SELF * load1any(bc, c, wf) + C_CROSS * p1[c] + C_DBL * acc;
  }
}

// z2sim = Rs@Mss + C_CROSS*(Rc@P2) + bsim ; z2cor = Rc@Mcc + C_CROSS*(Rs@P1) + bcor
// OUTPUT IS FLOAT32 (reference returns jnp.float32; inputs proven f32 in round 3).
__global__ __launch_bounds__(256) void finalmm(
    const unsigned short* __restrict__ Rs, const unsigned short* __restrict__ Rc,
    const float* __restrict__ Mss, const float* __restrict__ Mcc,
    const float* __restrict__ P1, const float* __restrict__ P2,
    const float* __restrict__ bsim, const float* __restrict__ bcor,
    float* __restrict__ outp)
{
  const int t = threadIdx.x;
  const int rt = t >> 5, ct = t & 31;
  const int r0 = blockIdx.x * 32 + rt * 4;
  const int c0 = ct * 4;
  float sA[4][4] = {}, sB[4][4] = {}, cA[4][4] = {}, cB[4][4] = {};

  for (int k = 0; k < 128; k += 4) {
    float a_s[4][4], a_c[4][4];
#pragma unroll
    for (int i = 0; i < 4; ++i) {
      load4bf(Rs + (size_t)(r0 + i) * H + k, a_s[i]);
      load4bf(Rc + (size_t)(r0 + i) * H + k, a_c[i]);
    }
#pragma unroll
    for (int kk = 0; kk < 4; ++kk) {
      float4 mss = *(const float4*)(Mss + (size_t)(k + kk) * H + c0);
      float4 mcc = *(const float4*)(Mcc + (size_t)(k + kk) * H + c0);
      float4 pp1 = *(const float4*)(P1 + (size_t)(k + kk) * H + c0);
      float4 pp2 = *(const float4*)(P2 + (size_t)(k + kk) * H + c0);
#pragma unroll
      for (int i = 0; i < 4; ++i) {
        const float as = a_s[i][kk], ac = a_c[i][kk];
        sA[i][0] += as * mss.x; sA[i][1] += as * mss.y; sA[i][2] += as * mss.z; sA[i][3] += as * mss.w;
        cB[i][0] += as * pp1.x; cB[i][1] += as * pp1.y; cB[i][2] += as * pp1.z; cB[i][3] += as * pp1.w;
        sB[i][0] += ac * pp2.x; sB[i][1] += ac * pp2.y; sB[i][2] += ac * pp2.z; sB[i][3] += ac * pp2.w;
        cA[i][0] += ac * mcc.x; cA[i][1] += ac * mcc.y; cA[i][2] += ac * mcc.z; cA[i][3] += ac * mcc.w;
      }
    }
  }
  float4 bsv = *(const float4*)(bsim + c0);
  float4 bcv = *(const float4*)(bcor + c0);
#pragma unroll
  for (int i = 0; i < 4; ++i) {
    float4 o1, o2;
    o1.x = sA[i][0] + C_CROSS * sB[i][0] + bsv.x;
    o1.y = sA[i][1] + C_CROSS * sB[i][1] + bsv.y;
    o1.z = sA[i][2] + C_CROSS * sB[i][2] + bsv.z;
    o1.w = sA[i][3] + C_CROSS * sB[i][3] + bsv.w;
    *(float4*)(outp + (size_t)(r0 + i) * H + c0) = o1;
    o2.x = cA[i][0] + C_CROSS * cB[i][0] + bcv.x;
    o2.y = cA[i][1] + C_CROSS * cB[i][1] + bcv.y;
    o2.z = cA[i][2] + C_CROSS * cB[i][2] + bcv.z;
    o2.w = cA[i][3] + C_CROSS * cB[i][3] + bcv.w;
    *(float4*)(outp + (size_t)NDST * H + (size_t)(r0 + i) * H + c0) = o2;
  }
}

extern "C" void kernel_launch(void* const* d_in, const int* in_sizes, int n_in,
                              void* d_out, int out_size, void* d_ws, size_t ws_size,
                              hipStream_t stream) {
  const int* x    = (const int*)d_in[0];
  const int* nsim = (const int*)d_in[1];
  const int* ncor = (const int*)d_in[2];
  const void* emb0_sim = d_in[3];
  const void* emb1_sim = d_in[4];
  const void* emb0_cor = d_in[5];
  const void* emb1_cor = d_in[6];
  const void* W_in_sim  = d_in[7];
  const void* b_in_sim  = d_in[8];
  const void* W_in_cor  = d_in[9];
  const void* b_in_cor  = d_in[10];
  const void* W_out_sim = d_in[11];
  const void* b_out_sim = d_in[12];
  const void* W_out_cor = d_in[13];
  const void* b_out_cor = d_in[14];
  const void* W_sim2cor = d_in[15];
  const void* W_cor2sim = d_in[16];

  // bf16 scratch region first (tightly packed), then f32 small matrices, then flags.
  unsigned short* wsu = (unsigned short*)d_ws;
  unsigned short* feat_sim = wsu;                            // NSRC*H
  unsigned short* feat_cor = feat_sim + (size_t)NSRC * H;    // NSRC*H
  unsigned short* rst_sim  = feat_cor + (size_t)NSRC * H;    // NDST*H
  unsigned short* rst_cor  = rst_sim + (size_t)NDST * H;     // NDST*H
  float* fbase = (float*)(rst_cor + (size_t)NDST * H);
  float* P1  = fbase;                  // 128*128
  float* P2  = P1 + H * H;
  float* Mss = P2 + H * H;
  float* Mcc = Mss + H * H;
  float* p1v = Mcc + H * H;            // 128 each
  float* p2v = p1v + H;
  float* bsim = p2v + H;
  float* bcor = bsim + H;
  int* flags = (int*)(bcor + H);

  detect<<<1, 64, 0, stream>>>((const unsigned short*)W_in_sim, x, flags);
  smallmm1<<<258, 128, 0, stream>>>(W_out_sim, W_out_cor, W_sim2cor, W_cor2sim,
                                    b_out_sim, b_out_cor, flags, P1, P2, p1v, p2v);
  smallmm2<<<258, 128, 0, stream>>>(W_out_sim, W_out_cor, W_sim2cor, W_cor2sim,
                                    b_out_sim, b_out_cor, flags, P1, P2, p1v, p2v,
                                    Mss, Mcc, bsim, bcor);
  featgemm<<<NSRC / 32, 256, 0, stream>>>(x, emb0_sim, emb1_sim, W_in_sim, b_in_sim, flags, feat_sim);
  featgemm<<<NSRC / 32, 256, 0, stream>>>(x, emb0_cor, emb1_cor, W_in_cor, b_in_cor, flags, feat_cor);
  // mode 'sim': D = feat[neigh_cor], Q = feat[neigh_sim]
  coatt<<<NDST, 256, 0, stream>>>(feat_sim, ncor, nsim, rst_sim);
  // mode 'cor': D = feat[neigh_sim], Q = feat[neigh_cor]
  coatt<<<NDST, 256, 0, stream>>>(feat_cor, nsim, ncor, rst_cor);
  finalmm<<<NDST / 32, 256, 0, stream>>>(rst_sim, rst_cor, Mss, Mcc, P1, P2,
                                         bsim, bcor, (float*)d_out);
}